// Round 1
// baseline (476.854 us; speedup 1.0000x reference)
//
#include <hip/hip_runtime.h>
#include <math.h>

namespace {

constexpr int Bn    = 4;
constexpr int Hn    = 128;
constexpr int MODES = 256;
constexpr int NCn   = 65536;
constexpr int TN    = 128;   // tail n-tile per block

__device__ __forceinline__ float gelu_f(float v) {
    return 0.5f * v * (1.0f + erff(v * 0.70710678118654752440f));
}

// ---- tiny: lwT[h*H + k] = lin_w[k*H + h] -----------------------------------
__global__ void k_transpose_lw(const float* __restrict__ lin_w,
                               float* __restrict__ lwT) {
    int h = blockIdx.x;
    int k = threadIdx.x;
    lwT[h * Hn + k] = lin_w[k * Hn + h];
}

// ---- spectral: yr[b,k,m] = sum_h x[b,h,m]*w_real[h,k,m] + bias[k,m] --------
// block = (k, b), thread = m. w reads are contiguous along m (coalesced).
__global__ __launch_bounds__(256) void k_spectral(
        const float* __restrict__ x, const float* __restrict__ w_real,
        const float* __restrict__ w_imag, const float* __restrict__ bias,
        float* __restrict__ yr, float* __restrict__ yi) {
    const int m = threadIdx.x;   // 0..255
    const int k = blockIdx.x;    // 0..127
    const int b = blockIdx.y;    // 0..3
    float ar = 0.f, ai = 0.f;
    const float* xp = x + b * Hn * NCn + m;          // stride NCn over h
    const float* wr = w_real + k * MODES + m;        // stride Hn*MODES over h
    const float* wi = w_imag + k * MODES + m;
    #pragma unroll 4
    for (int h = 0; h < Hn; ++h) {
        float xv = xp[h * NCn];
        ar = fmaf(xv, wr[h * Hn * MODES], ar);
        ai = fmaf(xv, wi[h * Hn * MODES], ai);
    }
    ar += bias[k * NCn + m];     // fold bias (real path only, m < MODES)
    int o = (b * Hn + k) * MODES + m;
    yr[o] = ar;
    yi[o] = ai;
}

// ---- head (n < MODES): z[b,k,m] = gelu(sum_h y[b,h,m]*lin_w[k,h] (+lin_b)) -
__global__ __launch_bounds__(256) void k_head(
        const float* __restrict__ yr, const float* __restrict__ yi,
        const float* __restrict__ lin_w, const float* __restrict__ lin_b,
        float* __restrict__ out) {
    const int m = threadIdx.x;
    const int k = blockIdx.x;
    const int b = blockIdx.y;
    float ar = 0.f, ai = 0.f;
    const float* yrp = yr + b * Hn * MODES + m;
    const float* yip = yi + b * Hn * MODES + m;
    const float* lw  = lin_w + k * Hn;               // uniform -> scalar loads
    #pragma unroll 4
    for (int h = 0; h < Hn; ++h) {
        float w = lw[h];
        ar = fmaf(w, yrp[h * MODES], ar);
        ai = fmaf(w, yip[h * MODES], ai);
    }
    ar += lin_b[k];
    float2 o = make_float2(gelu_f(ar), gelu_f(ai));
    ((float2*)out)[(size_t)(b * Hn + k) * NCn + m] = o;
}

// ---- tail (n >= MODES): t[k,n] = gelu(lin_w@bias[:,n] + lin_b[k]) ----------
// written to all 4 batches (real), imag = 0. Store-bound.
__global__ __launch_bounds__(256, 2) void k_tail(
        const float* __restrict__ bias, const float* __restrict__ lwT,
        const float* __restrict__ lin_b, float* __restrict__ out) {
    __shared__ float bs[Hn][TN];                     // 64 KiB -> 2 blocks/CU
    const int n0 = MODES + blockIdx.x * TN;

    // stage bias[:, n0:n0+TN] into LDS, float4 coalesced
    for (int i = threadIdx.x; i < Hn * (TN / 4); i += 256) {
        int h = i >> 5;              // TN/4 = 32 float4 per row
        int j = (i & 31) << 2;
        *(float4*)&bs[h][j] = *(const float4*)&bias[h * NCn + n0 + j];
    }
    __syncthreads();

    const int tn = threadIdx.x & 15;   // 16 n-groups of 8
    const int tk = threadIdx.x >> 4;   // 16 k-groups of 8
    float acc[8][8];
    #pragma unroll
    for (int a = 0; a < 8; ++a)
        #pragma unroll
        for (int c = 0; c < 8; ++c) acc[a][c] = 0.f;

    const float* lwp = lwT + tk * 8;   // lwT[h*H + k], broadcast across lanes
    #pragma unroll 2
    for (int h = 0; h < Hn; ++h) {
        float4 b0 = *(const float4*)&bs[h][tn * 8];
        float4 b1 = *(const float4*)&bs[h][tn * 8 + 4];
        float4 w0 = *(const float4*)&lwp[h * Hn];
        float4 w1 = *(const float4*)&lwp[h * Hn + 4];
        float bv[8] = {b0.x, b0.y, b0.z, b0.w, b1.x, b1.y, b1.z, b1.w};
        float wv[8] = {w0.x, w0.y, w0.z, w0.w, w1.x, w1.y, w1.z, w1.w};
        #pragma unroll
        for (int a = 0; a < 8; ++a)
            #pragma unroll
            for (int c = 0; c < 8; ++c)
                acc[a][c] = fmaf(wv[a], bv[c], acc[a][c]);
    }

    // epilogue: gelu once, broadcast to 4 batches; each lane writes whole
    // 64B lines ({zr,0} float2 pairs packed as float4)
    #pragma unroll
    for (int a = 0; a < 8; ++a) {
        int k = tk * 8 + a;
        float lb = lin_b[k];
        float t[8];
        #pragma unroll
        for (int c = 0; c < 8; ++c) t[c] = gelu_f(acc[a][c] + lb);
        float4 pk[4];
        #pragma unroll
        for (int j = 0; j < 4; ++j)
            pk[j] = make_float4(t[2 * j], 0.f, t[2 * j + 1], 0.f);
        #pragma unroll
        for (int b = 0; b < Bn; ++b) {
            float4* dst = (float4*)out +
                (((size_t)(b * Hn + k) * NCn + n0 + tn * 8) >> 1);
            dst[0] = pk[0];
            dst[1] = pk[1];
            dst[2] = pk[2];
            dst[3] = pk[3];
        }
    }
}

}  // namespace

extern "C" void kernel_launch(void* const* d_in, const int* in_sizes, int n_in,
                              void* d_out, int out_size, void* d_ws, size_t ws_size,
                              hipStream_t stream) {
    const float* x      = (const float*)d_in[0];
    const float* w_real = (const float*)d_in[1];
    const float* w_imag = (const float*)d_in[2];
    const float* bias   = (const float*)d_in[3];
    const float* lin_w  = (const float*)d_in[4];
    const float* lin_b  = (const float*)d_in[5];
    float* out = (float*)d_out;

    float* yr  = (float*)d_ws;                 // B*H*MODES fp32 = 512 KiB
    float* yi  = yr + Bn * Hn * MODES;         // 512 KiB
    float* lwT = yi + Bn * Hn * MODES;         // 64 KiB

    hipLaunchKernelGGL(k_transpose_lw, dim3(Hn), dim3(Hn), 0, stream,
                       lin_w, lwT);
    hipLaunchKernelGGL(k_spectral, dim3(Hn, Bn), dim3(MODES), 0, stream,
                       x, w_real, w_imag, bias, yr, yi);
    hipLaunchKernelGGL(k_head, dim3(Hn, Bn), dim3(MODES), 0, stream,
                       yr, yi, lin_w, lin_b, out);
    hipLaunchKernelGGL(k_tail, dim3((NCn - MODES) / TN), dim3(256), 0, stream,
                       bias, lwT, lin_b, out);
}

// Round 3
// 418.972 us; speedup vs baseline: 1.1382x; 1.1382x over previous
//
#include <hip/hip_runtime.h>
#include <math.h>

namespace {

constexpr int Bn    = 4;
constexpr int Hn    = 128;
constexpr int MODES = 256;
constexpr int NCn   = 65536;
constexpr int TN    = 128;   // tail n-tile per block

typedef float nt_f2 __attribute__((ext_vector_type(2)));
typedef float nt_f4 __attribute__((ext_vector_type(4)));

__device__ __forceinline__ float gelu_f(float v) {
    return 0.5f * v * (1.0f + erff(v * 0.70710678118654752440f));
}

// ---- tiny: lwT[h*H + k] = lin_w[k*H + h] -----------------------------------
__global__ void k_transpose_lw(const float* __restrict__ lin_w,
                               float* __restrict__ lwT) {
    int h = blockIdx.x;
    int k = threadIdx.x;
    lwT[h * Hn + k] = lin_w[k * Hn + h];
}

// ---- spectral: yr[b,k,m] = sum_h x[b,h,m]*w_real[h,k,m] + bias[k,m] --------
// block = (k, b), thread = m. w reads are contiguous along m (coalesced).
__global__ __launch_bounds__(256) void k_spectral(
        const float* __restrict__ x, const float* __restrict__ w_real,
        const float* __restrict__ w_imag, const float* __restrict__ bias,
        float* __restrict__ yr, float* __restrict__ yi) {
    const int m = threadIdx.x;   // 0..255
    const int k = blockIdx.x;    // 0..127
    const int b = blockIdx.y;    // 0..3
    float ar = 0.f, ai = 0.f;
    const float* xp = x + b * Hn * NCn + m;          // stride NCn over h
    const float* wr = w_real + k * MODES + m;        // stride Hn*MODES over h
    const float* wi = w_imag + k * MODES + m;
    #pragma unroll 8
    for (int h = 0; h < Hn; ++h) {
        float xv = xp[h * NCn];
        ar = fmaf(xv, wr[h * Hn * MODES], ar);
        ai = fmaf(xv, wi[h * Hn * MODES], ai);
    }
    ar += bias[k * NCn + m];     // fold bias (real path only, m < MODES)
    int o = (b * Hn + k) * MODES + m;
    yr[o] = ar;
    yi[o] = ai;
}

// ---- head (n < MODES): z[b,k,m] = gelu(sum_h y[b,h,m]*lin_w[k,h] (+lin_b)) -
__global__ __launch_bounds__(256) void k_head(
        const float* __restrict__ yr, const float* __restrict__ yi,
        const float* __restrict__ lin_w, const float* __restrict__ lin_b,
        float* __restrict__ out) {
    const int m = threadIdx.x;
    const int k = blockIdx.x;
    const int b = blockIdx.y;
    float ar = 0.f, ai = 0.f;
    const float* yrp = yr + b * Hn * MODES + m;
    const float* yip = yi + b * Hn * MODES + m;
    const float* lw  = lin_w + k * Hn;               // uniform -> scalar loads
    #pragma unroll 8
    for (int h = 0; h < Hn; ++h) {
        float w = lw[h];
        ar = fmaf(w, yrp[h * MODES], ar);
        ai = fmaf(w, yip[h * MODES], ai);
    }
    ar += lin_b[k];
    nt_f2 o = {gelu_f(ar), gelu_f(ai)};
    __builtin_nontemporal_store(o,
        (nt_f2*)out + ((size_t)(b * Hn + k) * NCn + m));
}

// ---- tail (n >= MODES): t[k,n] = gelu(lin_w@bias[:,n] + lin_b[k]) ----------
// written to all 4 batches (real), imag = 0. Store-bound.
// Lane mapping: lane tn (0..15), acc pair p (0..3) owns modes 32p+2tn+{0,1},
// so each float4 store is CONTIGUOUS across the 16 tn lanes (256 B segment).
__global__ __launch_bounds__(256, 2) void k_tail(
        const float* __restrict__ bias, const float* __restrict__ lwT,
        const float* __restrict__ lin_b, float* __restrict__ out) {
    __shared__ float bs[Hn][TN];                     // 64 KiB -> 2 blocks/CU
    const int n0 = MODES + blockIdx.x * TN;

    // stage bias[:, n0:n0+TN] into LDS, float4 coalesced
    for (int i = threadIdx.x; i < Hn * (TN / 4); i += 256) {
        int h = i >> 5;              // TN/4 = 32 float4 per row
        int j = (i & 31) << 2;
        *(float4*)&bs[h][j] = *(const float4*)&bias[h * NCn + n0 + j];
    }
    __syncthreads();

    const int tn = threadIdx.x & 15;   // 16 n-groups
    const int tk = threadIdx.x >> 4;   // 16 k-groups of 8
    float acc[8][8];                   // [a = k-sub][c = 2p+q]
    #pragma unroll
    for (int a = 0; a < 8; ++a)
        #pragma unroll
        for (int c = 0; c < 8; ++c) acc[a][c] = 0.f;

    const float* lwp = lwT + tk * 8;   // lwT[h*H + k]
    #pragma unroll 2
    for (int h = 0; h < Hn; ++h) {
        float bv[8];
        #pragma unroll
        for (int p = 0; p < 4; ++p) {
            float2 v = *(const float2*)&bs[h][32 * p + 2 * tn];
            bv[2 * p]     = v.x;
            bv[2 * p + 1] = v.y;
        }
        float4 w0 = *(const float4*)&lwp[h * Hn];
        float4 w1 = *(const float4*)&lwp[h * Hn + 4];
        float wv[8] = {w0.x, w0.y, w0.z, w0.w, w1.x, w1.y, w1.z, w1.w};
        #pragma unroll
        for (int a = 0; a < 8; ++a)
            #pragma unroll
            for (int c = 0; c < 8; ++c)
                acc[a][c] = fmaf(wv[a], bv[c], acc[a][c]);
    }

    // epilogue: gelu once, broadcast to 4 batches. Store p covers modes
    // n0+32p+2tn+{0,1} as {real,0,real,0} -> contiguous 256 B per tk group.
    #pragma unroll
    for (int a = 0; a < 8; ++a) {
        int k = tk * 8 + a;
        float lb = lin_b[k];
        float t[8];
        #pragma unroll
        for (int c = 0; c < 8; ++c) t[c] = gelu_f(acc[a][c] + lb);
        #pragma unroll
        for (int b = 0; b < Bn; ++b) {
            size_t rowbase = (size_t)(b * Hn + k) * NCn;  // float2 units
            #pragma unroll
            for (int p = 0; p < 4; ++p) {
                nt_f4 pk = {t[2 * p], 0.f, t[2 * p + 1], 0.f};
                __builtin_nontemporal_store(pk,
                    (nt_f4*)out + ((rowbase + n0 + 32 * p + 2 * tn) >> 1));
            }
        }
    }
}

}  // namespace

extern "C" void kernel_launch(void* const* d_in, const int* in_sizes, int n_in,
                              void* d_out, int out_size, void* d_ws, size_t ws_size,
                              hipStream_t stream) {
    const float* x      = (const float*)d_in[0];
    const float* w_real = (const float*)d_in[1];
    const float* w_imag = (const float*)d_in[2];
    const float* bias   = (const float*)d_in[3];
    const float* lin_w  = (const float*)d_in[4];
    const float* lin_b  = (const float*)d_in[5];
    float* out = (float*)d_out;

    float* yr  = (float*)d_ws;                 // B*H*MODES fp32 = 512 KiB
    float* yi  = yr + Bn * Hn * MODES;         // 512 KiB
    float* lwT = yi + Bn * Hn * MODES;         // 64 KiB

    hipLaunchKernelGGL(k_transpose_lw, dim3(Hn), dim3(Hn), 0, stream,
                       lin_w, lwT);
    hipLaunchKernelGGL(k_spectral, dim3(Hn, Bn), dim3(MODES), 0, stream,
                       x, w_real, w_imag, bias, yr, yi);
    hipLaunchKernelGGL(k_head, dim3(Hn, Bn), dim3(MODES), 0, stream,
                       yr, yi, lin_w, lin_b, out);
    hipLaunchKernelGGL(k_tail, dim3((NCn - MODES) / TN), dim3(256), 0, stream,
                       bias, lwT, lin_b, out);
}